// Round 8
// baseline (338.057 us; speedup 1.0000x reference)
//
#include <hip/hip_runtime.h>
#include <hip/hip_bf16.h>
#include <math.h>
#include <stdint.h>

// Problem constants
#define E_ 8
#define R_ 32
#define D_ 1024
#define H_ 4096
#define NTOK 4096          // B*S
#define M_MAX 5120         // padded-token capacity (40 tiles of 128)
#define TILES_MAX 40
#define SCALING 0.03125f   // 1/R

typedef __attribute__((ext_vector_type(8))) __bf16 bf16x8;
typedef __attribute__((ext_vector_type(8))) unsigned short ushort8;
typedef __attribute__((ext_vector_type(4))) float floatx4;

__device__ __forceinline__ unsigned short f2b(float f) {
    union { float f; unsigned int i; } v; v.f = f;
    unsigned int x = v.i;
    x += 0x7fffu + ((x >> 16) & 1u);   // round-to-nearest-even
    return (unsigned short)(x >> 16);
}
// tanh-form GELU (max |err| vs exact erf-GELU ~1.5e-4)
__device__ __forceinline__ float gelu_fast(float v) {
    float u = v * (0.7978845608028654f + 0.0356774080857f * v * v);
    float t = __expf(-2.f * fabsf(u));
    float th = (1.f - t) * __builtin_amdgcn_rcpf(1.f + t);
    th = (u >= 0.f) ? th : -th;
    return 0.5f * v * (1.f + th);
}

#define GLOAD_LDS16(g, l) __builtin_amdgcn_global_load_lds( \
    (const __attribute__((address_space(1))) void*)(g),     \
    (__attribute__((address_space(3))) void*)(l), 16, 0, 0)

// ---------------------------------------------------------------------------
// Kernel 0: fused prep = weight fp32->bf16 conversion (blocks 0..5375) +
// router (blocks 5376..6399, one wave per token, fp32, fp32 outputs).
// ---------------------------------------------------------------------------
__global__ __launch_bounds__(256) void k_prep(
    const float* __restrict__ w1, const float* __restrict__ w2,
    const float* __restrict__ Ad, const float* __restrict__ Bd,
    const float* __restrict__ Au, const float* __restrict__ Bu,
    unsigned short* __restrict__ w1b, unsigned short* __restrict__ w2b,
    unsigned short* __restrict__ Adb, unsigned short* __restrict__ Bdb,
    unsigned short* __restrict__ Aub, unsigned short* __restrict__ Bub,
    const float* __restrict__ x, const float* __restrict__ rw,
    const float* __restrict__ rb,
    float* __restrict__ out, int* __restrict__ idx)
{
    if (blockIdx.x < 5376) {
        long g = ((long)blockIdx.x * 256 + threadIdx.x) * 8;
        const float* src; unsigned short* dst; long off;
        if      (g <  4194304L) { src = w1; dst = w1b; off = 0; }
        else if (g <  8388608L) { src = w2; dst = w2b; off = 4194304L; }
        else if (g <  8650752L) { src = Ad; dst = Adb; off = 8388608L; }
        else if (g <  9699328L) { src = Bd; dst = Bdb; off = 8650752L; }
        else if (g < 10747904L) { src = Au; dst = Aub; off = 9699328L; }
        else                    { src = Bu; dst = Bub; off = 10747904L; }
        long i = g - off;
        float4 a = *(const float4*)(src + i);
        float4 b = *(const float4*)(src + i + 4);
        ushort8 o;
        o[0] = f2b(a.x); o[1] = f2b(a.y); o[2] = f2b(a.z); o[3] = f2b(a.w);
        o[4] = f2b(b.x); o[5] = f2b(b.y); o[6] = f2b(b.z); o[7] = f2b(b.w);
        *(ushort8*)(dst + i) = o;
        return;
    }
    const int wave = threadIdx.x >> 6, lane = threadIdx.x & 63;
    const int t = (blockIdx.x - 5376) * 4 + wave;
    const float4* xr = (const float4*)(x + (size_t)t * D_);
    float4 xv[4];
#pragma unroll
    for (int s = 0; s < 4; ++s) xv[s] = xr[lane + 64 * s];
    float acc[E_];
#pragma unroll
    for (int e = 0; e < E_; ++e) {
        const float4* wr = (const float4*)(rw + (size_t)e * D_);
        float s = 0.f;
#pragma unroll
        for (int u = 0; u < 4; ++u) {
            float4 wv = wr[lane + 64 * u];
            s += xv[u].x * wv.x + xv[u].y * wv.y + xv[u].z * wv.z + xv[u].w * wv.w;
        }
        acc[e] = s;
    }
#pragma unroll
    for (int e = 0; e < E_; ++e) {
#pragma unroll
        for (int m = 32; m > 0; m >>= 1) acc[e] += __shfl_xor(acc[e], m, 64);
        acc[e] += rb[e];
    }
    int best = 0;
#pragma unroll
    for (int e = 1; e < E_; ++e) if (acc[e] > acc[best]) best = e;   // first-max (np.argmax)
    const float mx = acc[best];
    float pr[E_]; float se = 0.f;
#pragma unroll
    for (int e = 0; e < E_; ++e) { pr[e] = expf(acc[e] - mx); se += pr[e]; }
    const float inv = 1.f / se;
    if (lane < E_) {
        float r = pr[lane] * inv;
        out[(size_t)NTOK * D_ + (size_t)t * E_ + lane] = r;
        float maskv = (lane == best) ? 1.f : 0.f;
        out[(size_t)NTOK * D_ + (size_t)NTOK * E_ + (size_t)t * E_ + lane] = (maskv - r) + r;
    }
    if (lane == 0) idx[t] = best;
}

// ---------------------------------------------------------------------------
// Kernel 2: scan (1 block). Deterministic expert-sorted permutation, segments
// padded to multiples of 128 so every GEMM tile has a uniform expert.
// ---------------------------------------------------------------------------
__global__ __launch_bounds__(256) void k_scan(
    const int* __restrict__ idx, int* __restrict__ hdr,
    int* __restrict__ tile_e, int* __restrict__ gather)
{
    __shared__ int cnt[256][E_];
    __shared__ int tot[E_], base[E_];
    const int tid = threadIdx.x;
    for (int m = tid; m < M_MAX; m += 256) gather[m] = -1;
    int c[E_];
#pragma unroll
    for (int e = 0; e < E_; ++e) c[e] = 0;
    for (int t = tid * 16; t < tid * 16 + 16; ++t) c[idx[t] & 7]++;
#pragma unroll
    for (int e = 0; e < E_; ++e) cnt[tid][e] = c[e];
    __syncthreads();
    if (tid < E_) {
        int run = 0;
        for (int i = 0; i < 256; ++i) { int v = cnt[i][tid]; cnt[i][tid] = run; run += v; }
        tot[tid] = run;
    }
    __syncthreads();
    if (tid == 0) {
        int b = 0, tp = 0;
        for (int e = 0; e < E_; ++e) {
            base[e] = b;
            int nt = (tot[e] + 127) >> 7;
            for (int k = 0; k < nt; ++k) tile_e[tp++] = e;
            b += nt << 7;
        }
        hdr[0] = b;       // M_pad
        hdr[1] = tp;      // n_tiles
        for (int k = tp; k < TILES_MAX; ++k) tile_e[k] = 0;
    }
    __syncthreads();
    int p[E_];
#pragma unroll
    for (int e = 0; e < E_; ++e) p[e] = base[e] + cnt[tid][e];
    for (int t = tid * 16; t < tid * 16 + 16; ++t) { int e = idx[t] & 7; gather[p[e]++] = t; }
}

// ---------------------------------------------------------------------------
// Kernel 3: gather x rows (fp32) into expert-sorted bf16 Xg (zeros for pads).
// ---------------------------------------------------------------------------
__global__ __launch_bounds__(128) void k_gather(
    const float* __restrict__ x, const int* __restrict__ gather,
    unsigned short* __restrict__ xg)
{
    const int m = blockIdx.x, tid = threadIdx.x;
    const int t = gather[m];
    ushort8* dst = (ushort8*)(xg + (size_t)m * D_);
    ushort8 o;
    if ((unsigned)t < (unsigned)NTOK) {
        const float4* src = (const float4*)(x + (size_t)t * D_);
        float4 a = src[tid * 2], b = src[tid * 2 + 1];
        o[0] = f2b(a.x); o[1] = f2b(a.y); o[2] = f2b(a.z); o[3] = f2b(a.w);
        o[4] = f2b(b.x); o[5] = f2b(b.y); o[6] = f2b(b.z); o[7] = f2b(b.w);
    } else {
        o = (ushort8)(0);
    }
    dst[tid] = o;
}

// ---------------------------------------------------------------------------
// Kernel 4/6: LoRA A-stage, single pass. Block = 32 m-rows x 32 ranks; the 4
// waves split K, LDS-reduce, add Ab, pre-scale by 1/R, write bf16 [M_MAX,32].
// ---------------------------------------------------------------------------
__global__ __launch_bounds__(256) void k_lora_a2(
    const unsigned short* __restrict__ A,    // [M_MAX, Ktot] bf16 (Xg or a_g)
    const unsigned short* __restrict__ W,    // [E, 32, Ktot] bf16 (converted)
    const float* __restrict__ Ab,            // [E, 32] fp32
    const int* __restrict__ hdr, const int* __restrict__ tile_e,
    unsigned short* __restrict__ outb,       // [M_MAX, 32] bf16 pre-scaled
    int Ktot)
{
    const int mtile = blockIdx.y;
    int ntiles = hdr[1]; if (ntiles > TILES_MAX) ntiles = TILES_MAX;
    if (mtile >= ntiles) return;
    const int e = tile_e[mtile] & 7;
    const int m0 = mtile * 128 + blockIdx.x * 32;
    const int wave = threadIdx.x >> 6, lane = threadIdx.x & 63;
    const int q = lane >> 4, l16 = lane & 15;
    const int Ks = Ktot >> 2;
    const int kbase = wave * Ks;
    const floatx4 z4 = {0.f, 0.f, 0.f, 0.f};
    floatx4 acc[2][2] = {{z4, z4}, {z4, z4}};
    const bf16x8* A0 = (const bf16x8*)(A + (size_t)(m0 + l16) * Ktot);
    const bf16x8* A1 = (const bf16x8*)(A + (size_t)(m0 + 16 + l16) * Ktot);
    const bf16x8* W0 = (const bf16x8*)(W + ((size_t)e * 32 + l16) * Ktot);
    const bf16x8* W1 = (const bf16x8*)(W + ((size_t)e * 32 + 16 + l16) * Ktot);
    for (int k = kbase; k < kbase + Ks; k += 32) {
        int u = (k >> 3) + q;
        bf16x8 a0 = A0[u], a1 = A1[u];
        bf16x8 b0 = W0[u], b1 = W1[u];
        acc[0][0] = __builtin_amdgcn_mfma_f32_16x16x32_bf16(a0, b0, acc[0][0], 0, 0, 0);
        acc[0][1] = __builtin_amdgcn_mfma_f32_16x16x32_bf16(a0, b1, acc[0][1], 0, 0, 0);
        acc[1][0] = __builtin_amdgcn_mfma_f32_16x16x32_bf16(a1, b0, acc[1][0], 0, 0, 0);
        acc[1][1] = __builtin_amdgcn_mfma_f32_16x16x32_bf16(a1, b1, acc[1][1], 0, 0, 0);
    }
    __shared__ float red[4][32][32];
#pragma unroll
    for (int mi = 0; mi < 2; ++mi)
#pragma unroll
        for (int ni = 0; ni < 2; ++ni)
#pragma unroll
            for (int r = 0; r < 4; ++r)
                red[wave][mi * 16 + q * 4 + r][ni * 16 + l16] = acc[mi][ni][r];
    __syncthreads();
    for (int i = threadIdx.x; i < 1024; i += 256) {
        int lr = i >> 5, c = i & 31;
        float s = red[0][lr][c] + red[1][lr][c] + red[2][lr][c] + red[3][lr][c];
        outb[(size_t)(m0 + lr) * 32 + c] = f2b(SCALING * (s + Ab[e * 32 + c]));
    }
}

// ---------------------------------------------------------------------------
// Main GEMM v6: 256x256 tile (2x FLOP per LDS byte vs 256x128 — the measured
// wall), 512 thr, 8 waves 2Mx4N, wave 128x64 (64 MFMA/K-tile), BK=64,
// double-buffered LDS (128 KiB). Front-loaded reads: all 24 ds_reads of tile
// t at tile start -> lgkmcnt(0) -> barrier (buffer fully consumed), then 4
// phases of {stage 1 half-tile of tile t+2 into the now-dead buffer (2
// gloads) + setprio + 16 MFMA + barrier}. vmcnt(6) at tile end => tile t+1
// fully landed, <=3 half-tiles of t+2 in flight (~2-tile lookahead).
// Zero-conflict swizzle algebra from R6 (measured 0). XCD-chunked mapping.
//   fc1: NSPLIT=1, grid (16,20) = 320 blocks.
//   fc2: NSPLIT=2, grid (4,20,2) = 160 blocks; z=1 -> P, k_reduce sums.
// ---------------------------------------------------------------------------
#define STG_A(U, KO) do { \
    GLOAD_LDS16(Ar + (size_t)((U) * 128)      * KTOT + (KO), As3 + bufo + (U) * 1024 +       wave * 64); \
    GLOAD_LDS16(Ar + (size_t)((U) * 128 + 64) * KTOT + (KO), As3 + bufo + (U) * 1024 + 512 + wave * 64); \
} while (0)
#define STG_B(U, KO) do { \
    GLOAD_LDS16(Br + (size_t)((U) * 128)      * KTOT + (KO), Bs3 + bufo + (U) * 1024 +       wave * 64); \
    GLOAD_LDS16(Br + (size_t)((U) * 128 + 64) * KTOT + (KO), Bs3 + bufo + (U) * 1024 + 512 + wave * 64); \
} while (0)

template <int KTOT, bool IS_FC1, int NSPLIT>
__global__ __launch_bounds__(512, 2) void k_mlp10(
    const unsigned short* __restrict__ Amat,   // [M_MAX, KTOT] bf16
    const unsigned short* __restrict__ Wmat,   // [NOUT, KTOT] bf16 (NT layout)
    const float* __restrict__ bias,            // [NOUT] fp32
    const unsigned short* __restrict__ lora_h, // [M_MAX, 32] pre-scaled bf16
    const unsigned short* __restrict__ lora_B, // [E, NOUT, 32] bf16
    const float* __restrict__ lora_b,          // [E, NOUT] fp32
    const int* __restrict__ hdr, const int* __restrict__ tile_e,
    const int* __restrict__ gather,
    unsigned short* __restrict__ outb,         // fc1: a_g bf16
    float* __restrict__ outf,                  // fc2: d_out fp32 (token order)
    float* __restrict__ P,                     // fc2 split-1 partials
    int NOUT)
{
    constexpr int NT = (KTOT / NSPLIT) / 64;   // K-tiles (fc1:16, fc2:32)
    int nt128 = hdr[1]; if (nt128 > TILES_MAX) nt128 = TILES_MAX;
    const int n256 = (nt128 + 1) >> 1;
    // Bijective XCD-chunked mapping over (x,y), y-major chunks.
    const int NXB = (int)gridDim.x;            // 16 (fc1) / 4 (fc2)
    const int NYB = (int)gridDim.y;            // 20
    const int nwg = NXB * NYB;                 // 320 / 80 (both %8 == 0)
    const int lid = (int)blockIdx.x + NXB * (int)blockIdx.y;
    const int tlin = (lid & 7) * (nwg >> 3) + (lid >> 3);
    const int mt2 = tlin % NYB;
    const int tx  = tlin / NYB;
    if (mt2 >= n256) return;
    const int m0 = mt2 * 256;
    const int h0 = tx * 256;
    const int kstart = (NSPLIT > 1) ? (int)blockIdx.z * (KTOT / NSPLIT) : 0;

    __shared__ bf16x8 As3[4096];               // 2 x [256][64] bf16 = 64 KiB
    __shared__ bf16x8 Bs3[4096];               // 2 x [256][64] bf16 = 64 KiB

    const int tid  = threadIdx.x;
    const int wave = tid >> 6, lane = tid & 63;
    const int l16 = lane & 15, q = lane >> 4;
    const int wm = wave & 1, wn = wave >> 1;   // 2M x 4N wave grid
    const int idx0 = q ^ (l16 & 7);            // swizzled 16B slot (kk=0)
    const int arow = wm * 128 + l16;           // + mi*16
    const int brow = wn * 64 + l16;            // + ni*16
    // staging geometry: 512 threads cover 64 rows x 8 slots per gload
    const int rrow = tid >> 3;
    const int jj8  = (((tid & 7) ^ (rrow & 7)) << 3);   // inverse-swizzled src
    const unsigned short* Abase = Amat + (size_t)m0 * KTOT + kstart;
    const unsigned short* Bbase = Wmat + (size_t)h0 * KTOT + kstart;
    const unsigned short* Ar = Abase + (size_t)rrow * KTOT + jj8;
    const unsigned short* Br = Bbase + (size_t)rrow * KTOT + jj8;

    const floatx4 z4 = {0.f, 0.f, 0.f, 0.f};
    floatx4 acc[8][4];
#pragma unroll
    for (int mi = 0; mi < 8; ++mi)
#pragma unroll
        for (int ni = 0; ni < 4; ++ni) acc[mi][ni] = z4;

    // prologue: stage tiles 0 (buf0) and 1 (buf1), 8 loads each; vmcnt(6)
    // leaves <=3 half-tiles of tile 1 outstanding (invariant entering t=0).
    {
        int bufo = 0;
        STG_A(0, 0); STG_A(1, 0); STG_B(0, 0); STG_B(1, 0);
        bufo = 2048;
        STG_A(0, 64); STG_A(1, 64); STG_B(0, 64); STG_B(1, 64);
    }
    asm volatile("s_waitcnt vmcnt(6)" ::: "memory");
    __builtin_amdgcn_s_barrier();

    int buf = 0;
#pragma unroll 1
    for (int kt = 0; kt < NT; ++kt) {
        const int bufo = buf << 11;            // 2048 bf16x8 per buffer
        const int ko2 = (kt + 2) << 6;
        const bool more = (kt + 2) < NT;
        // ---- front-loaded reads: all 24 frags of tile kt
        bf16x8 af[8][2], bfv[4][2];
#pragma unroll
        for (int mi = 0; mi < 8; ++mi) {
            const int rb8 = bufo + ((arow + mi * 16) << 3);
            af[mi][0] = As3[rb8 + idx0];
            af[mi][1] = As3[rb8 + (idx0 ^ 4)];
        }
#pragma unroll
        for (int ni = 0; ni < 4; ++ni) {
            const int rb8 = bufo + ((brow + ni * 16) << 3);
            bfv[ni][0] = Bs3[rb8 + idx0];
            bfv[ni][1] = Bs3[rb8 + (idx0 ^ 4)];
        }
        asm volatile("s_waitcnt lgkmcnt(0)" ::: "memory");
        __builtin_amdgcn_s_barrier();          // buffer `buf` fully consumed
        // ---- phase 0: stage A-half0 of tile kt+2 (same buf, now dead)
        if (more) STG_A(0, ko2);
        __builtin_amdgcn_s_setprio(1);
#pragma unroll
        for (int mi = 0; mi < 4; ++mi)
#pragma unroll
            for (int ni = 0; ni < 4; ++ni)
                acc[mi][ni] = __builtin_amdgcn_mfma_f32_16x16x32_bf16(af[mi][0], bfv[ni][0], acc[mi][ni], 0, 0, 0);
        __builtin_amdgcn_s_setprio(0);
        __builtin_amdgcn_s_barrier();
        // ---- phase 1: stage A-half1; MFMA (mihi, kk0)
        if (more) STG_A(1, ko2);
        __builtin_amdgcn_s_setprio(1);
#pragma unroll
        for (int mi = 4; mi < 8; ++mi)
#pragma unroll
            for (int ni = 0; ni < 4; ++ni)
                acc[mi][ni] = __builtin_amdgcn_mfma_f32_16x16x32_bf16(af[mi][0], bfv[ni][0], acc[mi][ni], 0, 0, 0);
        __builtin_amdgcn_s_setprio(0);
        __builtin_amdgcn_s_barrier();
        // ---- phase 2: stage B-half0; MFMA (milo, kk1)
        if (more) STG_B(0, ko2);
        __builtin_amdgcn_s_setprio(1);
#pragma unroll
        for (int mi = 0; mi < 4; ++mi)
#pragma unroll
            for (int ni = 0; ni < 4; ++ni)
                acc[mi][ni] = __builtin_amdgcn_mfma_f32_16x16x32_bf16(af[mi][1], bfv[ni][1], acc[mi][ni], 0, 0, 0);
        __builtin_amdgcn_s_setprio(0);
        __builtin_amdgcn_s_barrier();
        // ---- phase 3: stage B-half1; MFMA (mihi, kk1); tile-end vmcnt
        if (more) STG_B(1, ko2);
        __builtin_amdgcn_s_setprio(1);
#pragma unroll
        for (int mi = 4; mi < 8; ++mi)
#pragma unroll
            for (int ni = 0; ni < 4; ++ni)
                acc[mi][ni] = __builtin_amdgcn_mfma_f32_16x16x32_bf16(af[mi][1], bfv[ni][1], acc[mi][ni], 0, 0, 0);
        __builtin_amdgcn_s_setprio(0);
        if (more) asm volatile("s_waitcnt vmcnt(6)" ::: "memory");
        else      asm volatile("s_waitcnt vmcnt(0)" ::: "memory");
        __builtin_amdgcn_s_barrier();          // tile kt+1 published
        buf ^= 1;
    }

    // ---- fused LoRA-B epilogue (split 0 only): K=32 MFMA per subtile.
    const bool extras = (NSPLIT == 1) || (blockIdx.z == 0);
    const int e = tile_e[(mt2 << 1) + wm] & 7;
    if (extras) {
        bf16x8 a2[8], b2[4];
#pragma unroll
        for (int mi = 0; mi < 8; ++mi)
            a2[mi] = *(const bf16x8*)(lora_h + (size_t)(m0 + wm * 128 + mi * 16 + l16) * 32 + q * 8);
#pragma unroll
        for (int ni = 0; ni < 4; ++ni)
            b2[ni] = *(const bf16x8*)(lora_B + ((size_t)e * NOUT + h0 + wn * 64 + ni * 16 + l16) * 32 + q * 8);
#pragma unroll
        for (int mi = 0; mi < 8; ++mi)
#pragma unroll
            for (int ni = 0; ni < 4; ++ni)
                acc[mi][ni] = __builtin_amdgcn_mfma_f32_16x16x32_bf16(a2[mi], b2[ni], acc[mi][ni], 0, 0, 0);
    }

#pragma unroll
    for (int ni = 0; ni < 4; ++ni) {
        const int gh = h0 + wn * 64 + ni * 16 + l16;
        const float bv = extras ? (bias[gh] + SCALING * lora_b[e * NOUT + gh]) : 0.f;
#pragma unroll
        for (int mi = 0; mi < 8; ++mi) {
            const int gmb = m0 + wm * 128 + mi * 16 + q * 4;
#pragma unroll
            for (int r = 0; r < 4; ++r) {
                const int gm = gmb + r;
                const float v = acc[mi][ni][r] + bv;
                if (IS_FC1) {
                    outb[(size_t)gm * NOUT + gh] = f2b(gelu_fast(v));
                } else if (extras) {
                    const int t = gather[gm];
                    if ((unsigned)t < (unsigned)NTOK) outf[(size_t)t * NOUT + gh] = v;
                } else {
                    P[(size_t)gm * NOUT + gh] = v;
                }
            }
        }
    }
}

// ---------------------------------------------------------------------------
// Kernel 8: reduce fc2 split-1 partials into token-order out. One block/row.
// ---------------------------------------------------------------------------
__global__ __launch_bounds__(256) void k_reduce(
    const float* __restrict__ P, const int* __restrict__ gather,
    float* __restrict__ out)
{
    const int m = blockIdx.x;
    const int t = gather[m];
    if ((unsigned)t >= (unsigned)NTOK) return;
    const float4* p4 = (const float4*)(P + (size_t)m * D_);
    float4* o4 = (float4*)(out + (size_t)t * D_);
    int i = threadIdx.x;                      // D_/4 = 256
    float4 a = o4[i], b = p4[i];
    a.x += b.x; a.y += b.y; a.z += b.z; a.w += b.w;
    o4[i] = a;
}

// ---------------------------------------------------------------------------
// Workspace layout (bytes). P (fc2 split-1 partials, 21.0 MB) overlays the
// xg/w1b/Adb/Bdb region — all dead before fc2 runs.
// ---------------------------------------------------------------------------
#define OFF_IDX      0u
#define OFF_HDR      16384u
#define OFF_TILE     16640u
#define OFF_GATHER   16896u        // ends 37376
#define OFF_XG       37376u        // 10,485,760
#define OFF_W1B      10523136u     // 8,388,608
#define OFF_ADB      18911744u     // 524,288
#define OFF_BDB      19436032u     // 2,097,152
#define OFF_HSB      21533184u     // 327,680 -> ends 21,860,864
#define OFF_P        37376u        // 20,971,520 (overlay, ends 21,008,896)
#define OFF_AG       21860864u     // 41,943,040
#define OFF_HUB      63803904u     // 327,680
#define OFF_W2B      64131584u     // 8,388,608
#define OFF_AUB      72520192u     // 2,097,152
#define OFF_BUB      74617344u     // 524,288
#define WS_NEEDED    75141632u

extern "C" void kernel_launch(void* const* d_in, const int* in_sizes, int n_in,
                              void* d_out, int out_size, void* d_ws, size_t ws_size,
                              hipStream_t stream)
{
    (void)out_size;
    if (ws_size < (size_t)WS_NEEDED) return;
    if (n_in < 15 || in_sizes[0] != NTOK * D_ || in_sizes[3] != H_ * D_ ||
        in_sizes[5] != D_ * H_ || in_sizes[9] != E_ * H_ * R_) return;

    const float* x   = (const float*)d_in[0];
    const float* rw  = (const float*)d_in[1];
    const float* rb  = (const float*)d_in[2];
    const float* w1  = (const float*)d_in[3];
    const float* b1  = (const float*)d_in[4];
    const float* w2  = (const float*)d_in[5];
    const float* b2  = (const float*)d_in[6];
    const float* Ad  = (const float*)d_in[7];
    const float* Abd = (const float*)d_in[8];
    const float* Bd  = (const float*)d_in[9];
    const float* Bbd = (const float*)d_in[10];
    const float* Au  = (const float*)d_in[11];
    const float* Abu = (const float*)d_in[12];
    const float* Bu  = (const float*)d_in[13];
    const float* Bbu = (const float*)d_in[14];
    float* out = (float*)d_out;
    char* ws = (char*)d_ws;

    int* idx            = (int*)(ws + OFF_IDX);
    int* hdr            = (int*)(ws + OFF_HDR);
    int* tile_e         = (int*)(ws + OFF_TILE);
    int* gather         = (int*)(ws + OFF_GATHER);
    unsigned short* xg  = (unsigned short*)(ws + OFF_XG);
    unsigned short* hsb = (unsigned short*)(ws + OFF_HSB);
    unsigned short* ag  = (unsigned short*)(ws + OFF_AG);
    unsigned short* hub = (unsigned short*)(ws + OFF_HUB);
    unsigned short* w1b = (unsigned short*)(ws + OFF_W1B);
    unsigned short* w2b = (unsigned short*)(ws + OFF_W2B);
    unsigned short* Adb = (unsigned short*)(ws + OFF_ADB);
    unsigned short* Bdb = (unsigned short*)(ws + OFF_BDB);
    unsigned short* Aub = (unsigned short*)(ws + OFF_AUB);
    unsigned short* Bub = (unsigned short*)(ws + OFF_BUB);
    float* P            = (float*)(ws + OFF_P);

    // prep = weight cvt (5376 blocks) + router (1024 blocks)
    k_prep<<<6400, 256, 0, stream>>>(w1, w2, Ad, Bd, Au, Bu,
                                     w1b, w2b, Adb, Bdb, Aub, Bub,
                                     x, rw, rb, out, idx);
    k_scan<<<1, 256, 0, stream>>>(idx, hdr, tile_e, gather);
    k_gather<<<M_MAX, 128, 0, stream>>>(x, gather, xg);
    k_lora_a2<<<dim3(4, TILES_MAX), 256, 0, stream>>>(xg, Adb, Abd, hdr, tile_e, hsb, D_);
    k_mlp10<D_, true, 1><<<dim3(H_ / 256, TILES_MAX / 2, 1), 512, 0, stream>>>(
        xg, w1b, b1, hsb, Bdb, Bbd, hdr, tile_e, gather, ag, nullptr, nullptr, H_);
    k_lora_a2<<<dim3(4, TILES_MAX), 256, 0, stream>>>(ag, Aub, Abu, hdr, tile_e, hub, H_);
    k_mlp10<H_, false, 2><<<dim3(D_ / 256, TILES_MAX / 2, 2), 512, 0, stream>>>(
        ag, w2b, b2, hub, Bub, Bbu, hdr, tile_e, gather, nullptr, out, P, D_);
    k_reduce<<<M_MAX, 256, 0, stream>>>(P, gather, out);
}

// Round 9
// 335.350 us; speedup vs baseline: 1.0081x; 1.0081x over previous
//
#include <hip/hip_runtime.h>
#include <hip/hip_bf16.h>
#include <math.h>
#include <stdint.h>

// Problem constants
#define E_ 8
#define R_ 32
#define D_ 1024
#define H_ 4096
#define NTOK 4096          // B*S
#define M_MAX 5120         // padded-token capacity (40 tiles of 128)
#define TILES_MAX 40
#define SCALING 0.03125f   // 1/R

typedef __attribute__((ext_vector_type(8))) __bf16 bf16x8;
typedef __attribute__((ext_vector_type(8))) unsigned short ushort8;
typedef __attribute__((ext_vector_type(4))) float floatx4;

__device__ __forceinline__ unsigned short f2b(float f) {
    union { float f; unsigned int i; } v; v.f = f;
    unsigned int x = v.i;
    x += 0x7fffu + ((x >> 16) & 1u);   // round-to-nearest-even
    return (unsigned short)(x >> 16);
}
// tanh-form GELU (max |err| vs exact erf-GELU ~1.5e-4)
__device__ __forceinline__ float gelu_fast(float v) {
    float u = v * (0.7978845608028654f + 0.0356774080857f * v * v);
    float t = __expf(-2.f * fabsf(u));
    float th = (1.f - t) * __builtin_amdgcn_rcpf(1.f + t);
    th = (u >= 0.f) ? th : -th;
    return 0.5f * v * (1.f + th);
}

#define GLOAD_LDS16(g, l) __builtin_amdgcn_global_load_lds( \
    (const __attribute__((address_space(1))) void*)(g),     \
    (__attribute__((address_space(3))) void*)(l), 16, 0, 0)

// ---------------------------------------------------------------------------
// Kernel 0: fused prep = weight fp32->bf16 conversion (blocks 0..5375) +
// router (blocks 5376..6399, one wave per token, fp32, fp32 outputs).
// ---------------------------------------------------------------------------
__global__ __launch_bounds__(256) void k_prep(
    const float* __restrict__ w1, const float* __restrict__ w2,
    const float* __restrict__ Ad, const float* __restrict__ Bd,
    const float* __restrict__ Au, const float* __restrict__ Bu,
    unsigned short* __restrict__ w1b, unsigned short* __restrict__ w2b,
    unsigned short* __restrict__ Adb, unsigned short* __restrict__ Bdb,
    unsigned short* __restrict__ Aub, unsigned short* __restrict__ Bub,
    const float* __restrict__ x, const float* __restrict__ rw,
    const float* __restrict__ rb,
    float* __restrict__ out, int* __restrict__ idx)
{
    if (blockIdx.x < 5376) {
        long g = ((long)blockIdx.x * 256 + threadIdx.x) * 8;
        const float* src; unsigned short* dst; long off;
        if      (g <  4194304L) { src = w1; dst = w1b; off = 0; }
        else if (g <  8388608L) { src = w2; dst = w2b; off = 4194304L; }
        else if (g <  8650752L) { src = Ad; dst = Adb; off = 8388608L; }
        else if (g <  9699328L) { src = Bd; dst = Bdb; off = 8650752L; }
        else if (g < 10747904L) { src = Au; dst = Aub; off = 9699328L; }
        else                    { src = Bu; dst = Bub; off = 10747904L; }
        long i = g - off;
        float4 a = *(const float4*)(src + i);
        float4 b = *(const float4*)(src + i + 4);
        ushort8 o;
        o[0] = f2b(a.x); o[1] = f2b(a.y); o[2] = f2b(a.z); o[3] = f2b(a.w);
        o[4] = f2b(b.x); o[5] = f2b(b.y); o[6] = f2b(b.z); o[7] = f2b(b.w);
        *(ushort8*)(dst + i) = o;
        return;
    }
    const int wave = threadIdx.x >> 6, lane = threadIdx.x & 63;
    const int t = (blockIdx.x - 5376) * 4 + wave;
    const float4* xr = (const float4*)(x + (size_t)t * D_);
    float4 xv[4];
#pragma unroll
    for (int s = 0; s < 4; ++s) xv[s] = xr[lane + 64 * s];
    float acc[E_];
#pragma unroll
    for (int e = 0; e < E_; ++e) {
        const float4* wr = (const float4*)(rw + (size_t)e * D_);
        float s = 0.f;
#pragma unroll
        for (int u = 0; u < 4; ++u) {
            float4 wv = wr[lane + 64 * u];
            s += xv[u].x * wv.x + xv[u].y * wv.y + xv[u].z * wv.z + xv[u].w * wv.w;
        }
        acc[e] = s;
    }
#pragma unroll
    for (int e = 0; e < E_; ++e) {
#pragma unroll
        for (int m = 32; m > 0; m >>= 1) acc[e] += __shfl_xor(acc[e], m, 64);
        acc[e] += rb[e];
    }
    int best = 0;
#pragma unroll
    for (int e = 1; e < E_; ++e) if (acc[e] > acc[best]) best = e;   // first-max (np.argmax)
    const float mx = acc[best];
    float pr[E_]; float se = 0.f;
#pragma unroll
    for (int e = 0; e < E_; ++e) { pr[e] = expf(acc[e] - mx); se += pr[e]; }
    const float inv = 1.f / se;
    if (lane < E_) {
        float r = pr[lane] * inv;
        out[(size_t)NTOK * D_ + (size_t)t * E_ + lane] = r;
        float maskv = (lane == best) ? 1.f : 0.f;
        out[(size_t)NTOK * D_ + (size_t)NTOK * E_ + (size_t)t * E_ + lane] = (maskv - r) + r;
    }
    if (lane == 0) idx[t] = best;
}

// ---------------------------------------------------------------------------
// Kernel 2: scan (1 block). Deterministic expert-sorted permutation, segments
// padded to multiples of 128 so every GEMM tile has a uniform expert.
// ---------------------------------------------------------------------------
__global__ __launch_bounds__(256) void k_scan(
    const int* __restrict__ idx, int* __restrict__ hdr,
    int* __restrict__ tile_e, int* __restrict__ gather)
{
    __shared__ int cnt[256][E_];
    __shared__ int tot[E_], base[E_];
    const int tid = threadIdx.x;
    for (int m = tid; m < M_MAX; m += 256) gather[m] = -1;
    int c[E_];
#pragma unroll
    for (int e = 0; e < E_; ++e) c[e] = 0;
    for (int t = tid * 16; t < tid * 16 + 16; ++t) c[idx[t] & 7]++;
#pragma unroll
    for (int e = 0; e < E_; ++e) cnt[tid][e] = c[e];
    __syncthreads();
    if (tid < E_) {
        int run = 0;
        for (int i = 0; i < 256; ++i) { int v = cnt[i][tid]; cnt[i][tid] = run; run += v; }
        tot[tid] = run;
    }
    __syncthreads();
    if (tid == 0) {
        int b = 0, tp = 0;
        for (int e = 0; e < E_; ++e) {
            base[e] = b;
            int nt = (tot[e] + 127) >> 7;
            for (int k = 0; k < nt; ++k) tile_e[tp++] = e;
            b += nt << 7;
        }
        hdr[0] = b;       // M_pad
        hdr[1] = tp;      // n_tiles
        for (int k = tp; k < TILES_MAX; ++k) tile_e[k] = 0;
    }
    __syncthreads();
    int p[E_];
#pragma unroll
    for (int e = 0; e < E_; ++e) p[e] = base[e] + cnt[tid][e];
    for (int t = tid * 16; t < tid * 16 + 16; ++t) { int e = idx[t] & 7; gather[p[e]++] = t; }
}

// ---------------------------------------------------------------------------
// Kernel 3: gather x rows (fp32) into expert-sorted bf16 Xg (zeros for pads).
// ---------------------------------------------------------------------------
__global__ __launch_bounds__(128) void k_gather(
    const float* __restrict__ x, const int* __restrict__ gather,
    unsigned short* __restrict__ xg)
{
    const int m = blockIdx.x, tid = threadIdx.x;
    const int t = gather[m];
    ushort8* dst = (ushort8*)(xg + (size_t)m * D_);
    ushort8 o;
    if ((unsigned)t < (unsigned)NTOK) {
        const float4* src = (const float4*)(x + (size_t)t * D_);
        float4 a = src[tid * 2], b = src[tid * 2 + 1];
        o[0] = f2b(a.x); o[1] = f2b(a.y); o[2] = f2b(a.z); o[3] = f2b(a.w);
        o[4] = f2b(b.x); o[5] = f2b(b.y); o[6] = f2b(b.z); o[7] = f2b(b.w);
    } else {
        o = (ushort8)(0);
    }
    dst[tid] = o;
}

// ---------------------------------------------------------------------------
// Kernel 4/6: LoRA A-stage, single pass. Block = 32 m-rows x 32 ranks; the 4
// waves split K, LDS-reduce, add Ab, pre-scale by 1/R, write bf16 [M_MAX,32].
// ---------------------------------------------------------------------------
__global__ __launch_bounds__(256) void k_lora_a2(
    const unsigned short* __restrict__ A,    // [M_MAX, Ktot] bf16 (Xg or a_g)
    const unsigned short* __restrict__ W,    // [E, 32, Ktot] bf16 (converted)
    const float* __restrict__ Ab,            // [E, 32] fp32
    const int* __restrict__ hdr, const int* __restrict__ tile_e,
    unsigned short* __restrict__ outb,       // [M_MAX, 32] bf16 pre-scaled
    int Ktot)
{
    const int mtile = blockIdx.y;
    int ntiles = hdr[1]; if (ntiles > TILES_MAX) ntiles = TILES_MAX;
    if (mtile >= ntiles) return;
    const int e = tile_e[mtile] & 7;
    const int m0 = mtile * 128 + blockIdx.x * 32;
    const int wave = threadIdx.x >> 6, lane = threadIdx.x & 63;
    const int q = lane >> 4, l16 = lane & 15;
    const int Ks = Ktot >> 2;
    const int kbase = wave * Ks;
    const floatx4 z4 = {0.f, 0.f, 0.f, 0.f};
    floatx4 acc[2][2] = {{z4, z4}, {z4, z4}};
    const bf16x8* A0 = (const bf16x8*)(A + (size_t)(m0 + l16) * Ktot);
    const bf16x8* A1 = (const bf16x8*)(A + (size_t)(m0 + 16 + l16) * Ktot);
    const bf16x8* W0 = (const bf16x8*)(W + ((size_t)e * 32 + l16) * Ktot);
    const bf16x8* W1 = (const bf16x8*)(W + ((size_t)e * 32 + 16 + l16) * Ktot);
    for (int k = kbase; k < kbase + Ks; k += 32) {
        int u = (k >> 3) + q;
        bf16x8 a0 = A0[u], a1 = A1[u];
        bf16x8 b0 = W0[u], b1 = W1[u];
        acc[0][0] = __builtin_amdgcn_mfma_f32_16x16x32_bf16(a0, b0, acc[0][0], 0, 0, 0);
        acc[0][1] = __builtin_amdgcn_mfma_f32_16x16x32_bf16(a0, b1, acc[0][1], 0, 0, 0);
        acc[1][0] = __builtin_amdgcn_mfma_f32_16x16x32_bf16(a1, b0, acc[1][0], 0, 0, 0);
        acc[1][1] = __builtin_amdgcn_mfma_f32_16x16x32_bf16(a1, b1, acc[1][1], 0, 0, 0);
    }
    __shared__ float red[4][32][32];
#pragma unroll
    for (int mi = 0; mi < 2; ++mi)
#pragma unroll
        for (int ni = 0; ni < 2; ++ni)
#pragma unroll
            for (int r = 0; r < 4; ++r)
                red[wave][mi * 16 + q * 4 + r][ni * 16 + l16] = acc[mi][ni][r];
    __syncthreads();
    for (int i = threadIdx.x; i < 1024; i += 256) {
        int lr = i >> 5, c = i & 31;
        float s = red[0][lr][c] + red[1][lr][c] + red[2][lr][c] + red[3][lr][c];
        outb[(size_t)(m0 + lr) * 32 + c] = f2b(SCALING * (s + Ab[e * 32 + c]));
    }
}

// ---------------------------------------------------------------------------
// Main GEMM v7 (m201-style): 256x256 tile, 512 thr, 8 waves 2Mx4N, per-wave
// 128x64 (64 MFMA/K-tile). dbuf-2 LDS (128 KiB). Per-phase SUBTILE reads
// (4-8 ds_read_b128, <=16 live frags) feeding 16-MFMA clusters; stages of
// tile kt+1 (into buf^1 — race-free under dbuf) interleaved 2-3 per phase.
// One mid-tile barrier + one end-of-tile vmcnt(0)+barrier (stages issue
// >=2 phases before the drain). setprio around each MFMA cluster.
// __launch_bounds__(512,1): ~200 VGPR allowed, no spill (2 waves/SIMD at
// 256 VGPR per m69). R6's zero-conflict swizzle + bijective XCD chunking.
//   fc1: NSPLIT=1, grid (16,20)=320 blocks.
//   fc2: NSPLIT=2, grid (4,20,2)=160 blocks; z=1 -> P, k_reduce sums.
// ---------------------------------------------------------------------------
#define STG_A(U, KO, SB) GLOAD_LDS16(Ar + (size_t)((U) * 64) * KTOT + (KO), \
                                     As3 + (SB) + (U) * 512 + wave * 64)
#define STG_B(U, KO, SB) GLOAD_LDS16(Br + (size_t)((U) * 64) * KTOT + (KO), \
                                     Bs3 + (SB) + (U) * 512 + wave * 64)

template <int KTOT, bool IS_FC1, int NSPLIT>
__global__ __launch_bounds__(512, 1) void k_mlp11(
    const unsigned short* __restrict__ Amat,   // [M_MAX, KTOT] bf16
    const unsigned short* __restrict__ Wmat,   // [NOUT, KTOT] bf16 (NT layout)
    const float* __restrict__ bias,            // [NOUT] fp32
    const unsigned short* __restrict__ lora_h, // [M_MAX, 32] pre-scaled bf16
    const unsigned short* __restrict__ lora_B, // [E, NOUT, 32] bf16
    const float* __restrict__ lora_b,          // [E, NOUT] fp32
    const int* __restrict__ hdr, const int* __restrict__ tile_e,
    const int* __restrict__ gather,
    unsigned short* __restrict__ outb,         // fc1: a_g bf16
    float* __restrict__ outf,                  // fc2: d_out fp32 (token order)
    float* __restrict__ P,                     // fc2 split-1 partials
    int NOUT)
{
    constexpr int NT = (KTOT / NSPLIT) / 64;   // K-tiles (fc1:16, fc2:32)
    int nt128 = hdr[1]; if (nt128 > TILES_MAX) nt128 = TILES_MAX;
    const int n256 = (nt128 + 1) >> 1;
    // Bijective XCD-chunked mapping over (x,y), y-major chunks.
    const int NXB = (int)gridDim.x;            // 16 (fc1) / 4 (fc2)
    const int NYB = (int)gridDim.y;            // 20
    const int nwg = NXB * NYB;                 // 320 / 80 (both %8 == 0)
    const int lid = (int)blockIdx.x + NXB * (int)blockIdx.y;
    const int tlin = (lid & 7) * (nwg >> 3) + (lid >> 3);
    const int mt2 = tlin % NYB;
    const int tx  = tlin / NYB;
    if (mt2 >= n256) return;
    const int m0 = mt2 * 256;
    const int h0 = tx * 256;
    const int kstart = (NSPLIT > 1) ? (int)blockIdx.z * (KTOT / NSPLIT) : 0;

    __shared__ bf16x8 As3[4096];               // 2 x [256][64] bf16 = 64 KiB
    __shared__ bf16x8 Bs3[4096];               // 2 x [256][64] bf16 = 64 KiB

    const int tid  = threadIdx.x;
    const int wave = tid >> 6, lane = tid & 63;
    const int l16 = lane & 15, q = lane >> 4;
    const int wm = wave & 1, wn = wave >> 1;   // 2M x 4N wave grid
    const int idx0 = q ^ (l16 & 7);            // swizzled 16B slot (kk=0)
    const int abase8 = (wm * 128 + l16) << 3;  // + (mi*16)<<3
    const int bbase8 = (wn * 64 + l16) << 3;   // + (ni*16)<<3
    // staging geometry: 512 threads cover 64 rows x 8 slots per gload
    const int rrow = tid >> 3;
    const int jj8  = (((tid & 7) ^ (rrow & 7)) << 3);   // inverse-swizzled src
    const unsigned short* Abase = Amat + (size_t)m0 * KTOT + kstart;
    const unsigned short* Bbase = Wmat + (size_t)h0 * KTOT + kstart;
    const unsigned short* Ar = Abase + (size_t)rrow * KTOT + jj8;
    const unsigned short* Br = Bbase + (size_t)rrow * KTOT + jj8;

    const floatx4 z4 = {0.f, 0.f, 0.f, 0.f};
    floatx4 acc[8][4];
#pragma unroll
    for (int mi = 0; mi < 8; ++mi)
#pragma unroll
        for (int ni = 0; ni < 4; ++ni) acc[mi][ni] = z4;

    // prologue: stage tile 0 into buf0 (8 gloads), drain, publish.
    STG_A(0, 0, 0); STG_A(1, 0, 0); STG_A(2, 0, 0); STG_A(3, 0, 0);
    STG_B(0, 0, 0); STG_B(1, 0, 0); STG_B(2, 0, 0); STG_B(3, 0, 0);
    asm volatile("s_waitcnt vmcnt(0)" ::: "memory");
    __builtin_amdgcn_s_barrier();

    int buf = 0;
#pragma unroll 1
    for (int kt = 0; kt < NT; ++kt) {
        const int bufo  = buf << 11;           // 2048 bf16x8 per buffer
        const int sbufo = (buf ^ 1) << 11;
        const int ko = (kt + 1) << 6;
        const bool more = (kt + 1) < NT;
        bf16x8 a0[4], a1[4], b0[4], b1[4];
        // ---- phase 0: read af[0..4)@kk0 + bfv@kk0; stage A0,A1; MFMA lo/kk0
#pragma unroll
        for (int mi = 0; mi < 4; ++mi) a0[mi] = As3[bufo + abase8 + (mi << 7) + idx0];
#pragma unroll
        for (int ni = 0; ni < 4; ++ni) b0[ni] = Bs3[bufo + bbase8 + (ni << 7) + idx0];
        if (more) { STG_A(0, ko, sbufo); STG_A(1, ko, sbufo); }
        __builtin_amdgcn_s_setprio(1);
#pragma unroll
        for (int mi = 0; mi < 4; ++mi)
#pragma unroll
            for (int ni = 0; ni < 4; ++ni)
                acc[mi][ni] = __builtin_amdgcn_mfma_f32_16x16x32_bf16(a0[mi], b0[ni], acc[mi][ni], 0, 0, 0);
        __builtin_amdgcn_s_setprio(0);
        // ---- phase 1: read af[4..8)@kk0; stage A2,A3; MFMA hi/kk0
#pragma unroll
        for (int mi = 0; mi < 4; ++mi) a1[mi] = As3[bufo + abase8 + ((mi + 4) << 7) + idx0];
        if (more) { STG_A(2, ko, sbufo); STG_A(3, ko, sbufo); }
        __builtin_amdgcn_s_setprio(1);
#pragma unroll
        for (int mi = 0; mi < 4; ++mi)
#pragma unroll
            for (int ni = 0; ni < 4; ++ni)
                acc[mi + 4][ni] = __builtin_amdgcn_mfma_f32_16x16x32_bf16(a1[mi], b0[ni], acc[mi + 4][ni], 0, 0, 0);
        __builtin_amdgcn_s_setprio(0);
        __builtin_amdgcn_s_barrier();          // mid-tile cohesion
        // ---- phase 2: read af[0..4)@kk1 + bfv@kk1; stage B0,B1; MFMA lo/kk1
#pragma unroll
        for (int mi = 0; mi < 4; ++mi) a0[mi] = As3[bufo + abase8 + (mi << 7) + (idx0 ^ 4)];
#pragma unroll
        for (int ni = 0; ni < 4; ++ni) b1[ni] = Bs3[bufo + bbase8 + (ni << 7) + (idx0 ^ 4)];
        if (more) { STG_B(0, ko, sbufo); STG_B(1, ko, sbufo); }
        __builtin_amdgcn_s_setprio(1);
#pragma unroll
        for (int mi = 0; mi < 4; ++mi)
#pragma unroll
            for (int ni = 0; ni < 4; ++ni)
                acc[mi][ni] = __builtin_amdgcn_mfma_f32_16x16x32_bf16(a0[mi], b1[ni], acc[mi][ni], 0, 0, 0);
        __builtin_amdgcn_s_setprio(0);
        // ---- phase 3: read af[4..8)@kk1; stage B2,B3; MFMA hi/kk1
#pragma unroll
        for (int mi = 0; mi < 4; ++mi) a1[mi] = As3[bufo + abase8 + ((mi + 4) << 7) + (idx0 ^ 4)];
        if (more) { STG_B(2, ko, sbufo); STG_B(3, ko, sbufo); }
        __builtin_amdgcn_s_setprio(1);
#pragma unroll
        for (int mi = 0; mi < 4; ++mi)
#pragma unroll
            for (int ni = 0; ni < 4; ++ni)
                acc[mi + 4][ni] = __builtin_amdgcn_mfma_f32_16x16x32_bf16(a1[mi], b1[ni], acc[mi + 4][ni], 0, 0, 0);
        __builtin_amdgcn_s_setprio(0);
        asm volatile("s_waitcnt vmcnt(0)" ::: "memory");
        __builtin_amdgcn_s_barrier();          // tile kt+1 published
        buf ^= 1;
    }

    // ---- fused LoRA-B epilogue (split 0 only): K=32 MFMA per subtile.
    const bool extras = (NSPLIT == 1) || (blockIdx.z == 0);
    const int e = tile_e[(mt2 << 1) + wm] & 7;
    if (extras) {
        bf16x8 a2[8], b2[4];
#pragma unroll
        for (int mi = 0; mi < 8; ++mi)
            a2[mi] = *(const bf16x8*)(lora_h + (size_t)(m0 + wm * 128 + mi * 16 + l16) * 32 + q * 8);
#pragma unroll
        for (int ni = 0; ni < 4; ++ni)
            b2[ni] = *(const bf16x8*)(lora_B + ((size_t)e * NOUT + h0 + wn * 64 + ni * 16 + l16) * 32 + q * 8);
#pragma unroll
        for (int mi = 0; mi < 8; ++mi)
#pragma unroll
            for (int ni = 0; ni < 4; ++ni)
                acc[mi][ni] = __builtin_amdgcn_mfma_f32_16x16x32_bf16(a2[mi], b2[ni], acc[mi][ni], 0, 0, 0);
    }

#pragma unroll
    for (int ni = 0; ni < 4; ++ni) {
        const int gh = h0 + wn * 64 + ni * 16 + l16;
        const float bv = extras ? (bias[gh] + SCALING * lora_b[e * NOUT + gh]) : 0.f;
#pragma unroll
        for (int mi = 0; mi < 8; ++mi) {
            const int gmb = m0 + wm * 128 + mi * 16 + q * 4;
#pragma unroll
            for (int r = 0; r < 4; ++r) {
                const int gm = gmb + r;
                const float v = acc[mi][ni][r] + bv;
                if (IS_FC1) {
                    outb[(size_t)gm * NOUT + gh] = f2b(gelu_fast(v));
                } else if (extras) {
                    const int t = gather[gm];
                    if ((unsigned)t < (unsigned)NTOK) outf[(size_t)t * NOUT + gh] = v;
                } else {
                    P[(size_t)gm * NOUT + gh] = v;
                }
            }
        }
    }
}

// ---------------------------------------------------------------------------
// Kernel 8: reduce fc2 split-1 partials into token-order out. One block/row.
// ---------------------------------------------------------------------------
__global__ __launch_bounds__(256) void k_reduce(
    const float* __restrict__ P, const int* __restrict__ gather,
    float* __restrict__ out)
{
    const int m = blockIdx.x;
    const int t = gather[m];
    if ((unsigned)t >= (unsigned)NTOK) return;
    const float4* p4 = (const float4*)(P + (size_t)m * D_);
    float4* o4 = (float4*)(out + (size_t)t * D_);
    int i = threadIdx.x;                      // D_/4 = 256
    float4 a = o4[i], b = p4[i];
    a.x += b.x; a.y += b.y; a.z += b.z; a.w += b.w;
    o4[i] = a;
}

// ---------------------------------------------------------------------------
// Workspace layout (bytes). P (fc2 split-1 partials, 21.0 MB) overlays the
// xg/w1b/Adb/Bdb region — all dead before fc2 runs.
// ---------------------------------------------------------------------------
#define OFF_IDX      0u
#define OFF_HDR      16384u
#define OFF_TILE     16640u
#define OFF_GATHER   16896u        // ends 37376
#define OFF_XG       37376u        // 10,485,760
#define OFF_W1B      10523136u     // 8,388,608
#define OFF_ADB      18911744u     // 524,288
#define OFF_BDB      19436032u     // 2,097,152
#define OFF_HSB      21533184u     // 327,680 -> ends 21,860,864
#define OFF_P        37376u        // 20,971,520 (overlay, ends 21,008,896)
#define OFF_AG       21860864u     // 41,943,040
#define OFF_HUB      63803904u     // 327,680
#define OFF_W2B      64131584u     // 8,388,608
#define OFF_AUB      72520192u     // 2,097,152
#define OFF_BUB      74617344u     // 524,288
#define WS_NEEDED    75141632u

extern "C" void kernel_launch(void* const* d_in, const int* in_sizes, int n_in,
                              void* d_out, int out_size, void* d_ws, size_t ws_size,
                              hipStream_t stream)
{
    (void)out_size;
    if (ws_size < (size_t)WS_NEEDED) return;
    if (n_in < 15 || in_sizes[0] != NTOK * D_ || in_sizes[3] != H_ * D_ ||
        in_sizes[5] != D_ * H_ || in_sizes[9] != E_ * H_ * R_) return;

    const float* x   = (const float*)d_in[0];
    const float* rw  = (const float*)d_in[1];
    const float* rb  = (const float*)d_in[2];
    const float* w1  = (const float*)d_in[3];
    const float* b1  = (const float*)d_in[4];
    const float* w2  = (const float*)d_in[5];
    const float* b2  = (const float*)d_in[6];
    const float* Ad  = (const float*)d_in[7];
    const float* Abd = (const float*)d_in[8];
    const float* Bd  = (const float*)d_in[9];
    const float* Bbd = (const float*)d_in[10];
    const float* Au  = (const float*)d_in[11];
    const float* Abu = (const float*)d_in[12];
    const float* Bu  = (const float*)d_in[13];
    const float* Bbu = (const float*)d_in[14];
    float* out = (float*)d_out;
    char* ws = (char*)d_ws;

    int* idx            = (int*)(ws + OFF_IDX);
    int* hdr            = (int*)(ws + OFF_HDR);
    int* tile_e         = (int*)(ws + OFF_TILE);
    int* gather         = (int*)(ws + OFF_GATHER);
    unsigned short* xg  = (unsigned short*)(ws + OFF_XG);
    unsigned short* hsb = (unsigned short*)(ws + OFF_HSB);
    unsigned short* ag  = (unsigned short*)(ws + OFF_AG);
    unsigned short* hub = (unsigned short*)(ws + OFF_HUB);
    unsigned short* w1b = (unsigned short*)(ws + OFF_W1B);
    unsigned short* w2b = (unsigned short*)(ws + OFF_W2B);
    unsigned short* Adb = (unsigned short*)(ws + OFF_ADB);
    unsigned short* Bdb = (unsigned short*)(ws + OFF_BDB);
    unsigned short* Aub = (unsigned short*)(ws + OFF_AUB);
    unsigned short* Bub = (unsigned short*)(ws + OFF_BUB);
    float* P            = (float*)(ws + OFF_P);

    // prep = weight cvt (5376 blocks) + router (1024 blocks)
    k_prep<<<6400, 256, 0, stream>>>(w1, w2, Ad, Bd, Au, Bu,
                                     w1b, w2b, Adb, Bdb, Aub, Bub,
                                     x, rw, rb, out, idx);
    k_scan<<<1, 256, 0, stream>>>(idx, hdr, tile_e, gather);
    k_gather<<<M_MAX, 128, 0, stream>>>(x, gather, xg);
    k_lora_a2<<<dim3(4, TILES_MAX), 256, 0, stream>>>(xg, Adb, Abd, hdr, tile_e, hsb, D_);
    k_mlp11<D_, true, 1><<<dim3(H_ / 256, TILES_MAX / 2, 1), 512, 0, stream>>>(
        xg, w1b, b1, hsb, Bdb, Bbd, hdr, tile_e, gather, ag, nullptr, nullptr, H_);
    k_lora_a2<<<dim3(4, TILES_MAX), 256, 0, stream>>>(ag, Aub, Abu, hdr, tile_e, hub, H_);
    k_mlp11<H_, false, 2><<<dim3(D_ / 256, TILES_MAX / 2, 2), 512, 0, stream>>>(
        ag, w2b, b2, hub, Bub, Bbu, hdr, tile_e, gather, nullptr, out, P, D_);
    k_reduce<<<M_MAX, 256, 0, stream>>>(P, gather, out);
}